// Round 14
// baseline (501.488 us; speedup 1.0000x reference)
//
#include <hip/hip_runtime.h>
#include <hip/hip_bf16.h>

// Max-tree (component tree) per channel, 64x64x3. Outputs (float32):
// parents [3,4096] then altitudes [3,4096].
//
// ranks = stable descending sort position (distinct, 0 = highest f) act as
// altitudes; rank-image max-tree's uncompressed pixel-parent == reference's
// (validated r2-r13). Distinct ranks => UNIQUE tree => order-independent
// incremental edge insertion via concurrent CAS splice-walks (r5-r13).
//
// r14 = r13 + two-phase cross insertion in K2:
//  Phase A: per boundary, ONLY the min-ry edge (the deep two-trunk
//           interleave) — 15 concurrent walks, no intra-boundary racing,
//           all in wave 0 (one vector ds_read per step for all 15).
//  Phase B: remaining 945 edges after barrier — walks ride matured
//           entry-compression hints. Order freedom => same unique tree.
//
// Safety (r5-r13, schedule/subset-agnostic): parw CAS is ABA-safe (non-root
// parent-rank strictly decreases; self word never recurs); climb on stale
// parent safe (splices only INSERT between x and parent); skipw hints are
// ancestors-or-self, jump guarded by rank<=ry (ranks strictly ascend along
// root paths; distinct ranks => rank==ry <=> node==y); racy 32-bit hint
// stores word-atomic. State stride 8B (16 banks) — never 16B (r11 lesson).
// Canon closed form g[p] = climb-from-parent-while-f-equal (validated r2-r13).

#define N_PIX 4096
#define CH 3

// ---------------------------------------------------------------------------
// K1: rank + intra-strip concurrent build. 48 blocks x 256 threads.
// ---------------------------------------------------------------------------
__global__ __launch_bounds__(256) void ct_rank_build(const float* __restrict__ vw,
                                                     int* __restrict__ rank_g,
                                                     unsigned* __restrict__ word_g) {
    __shared__ __align__(16) float vals[N_PIX];          // 16 KB
    __shared__ unsigned short rankS[256];
    __shared__ __align__(8) unsigned st[2 * 256];        // 2 KB (parw,skipw)
    const int c    = blockIdx.x >> 4;
    const int seg  = blockIdx.x & 15;
    const int tid  = threadIdx.x;
    const int base = seg << 8;

    for (int i = tid; i < N_PIX; i += 256) vals[i] = vw[i * CH + c];
    __syncthreads();

    // ---- global stable descending rank of this thread's pixel ----
    const int   p  = base + tid;
    const float vp = vals[p];
    int cnt = 0;
    const float4* v4 = reinterpret_cast<const float4*>(vals);
#pragma unroll 4
    for (int j4 = 0; j4 < N_PIX / 4; ++j4) {
        float4 q = v4[j4];
        int j = j4 << 2;
        cnt += (q.x > vp) || ((q.x == vp) && (j     < p));
        cnt += (q.y > vp) || ((q.y == vp) && (j + 1 < p));
        cnt += (q.z > vp) || ((q.z == vp) && (j + 2 < p));
        cnt += (q.w > vp) || ((q.w == vp) && (j + 3 < p));
    }
    rank_g[(c << 12) + p] = cnt;
    rankS[tid] = (unsigned short)cnt;
    const unsigned selfw = ((unsigned)cnt << 12) | (unsigned)p;  // global id
    st[2 * tid]     = selfw;                                     // parw (root)
    st[2 * tid + 1] = selfw;                                     // skipw (self)
    __syncthreads();

    // ---- insert 444 intra-strip edges (2 slots/thread), local indexing ----
    int xlA[2], pxA[2], x0A[2];
    unsigned ywA[2];
    unsigned act = 0;
#pragma unroll
    for (int k = 0; k < 2; ++k) {
        xlA[k] = 0; pxA[k] = -1; x0A[k] = 0; ywA[k] = 0;
        const int e = (k << 8) + tid;
        if (e < 444) {
            int xl, yl;
            if (e < 252) { const int lr = e / 63; xl = (lr << 6) + (e - lr * 63); yl = xl + 1; }
            else         { const int e2 = e - 252; xl = ((e2 >> 6) << 6) + (e2 & 63); yl = xl + 64; }
            unsigned rx = rankS[xl], ry = rankS[yl];
            if (rx > ry) { int t = xl; xl = yl; yl = t; unsigned tr = rx; rx = ry; ry = tr; }
            xlA[k]  = xl;
            x0A[k]  = xl;
            ywA[k]  = (ry << 12) | (unsigned)(base + yl);
            act    |= 1u << k;
        }
    }

    auto stepL = [&](int k, unsigned long long lv) {
        const int      xl = xlA[k];
        const unsigned xg = (unsigned)(base + xl);
        const unsigned yw = ywA[k];
        const unsigned ry = yw >> 12;
        const unsigned w  = (unsigned)lv;
        const unsigned sk = (unsigned)(lv >> 32);
        if (pxA[k] >= 0) { st[2 * pxA[k] + 1] = sk; pxA[k] = -1; }
        const unsigned s = sk & 0xFFFu;
        if (s != xg && (sk >> 12) <= ry) {                     // hint jump
            if (s == (yw & 0xFFFu)) { st[2 * x0A[k] + 1] = yw; act &= ~(1u << k); }
            else { pxA[k] = xl; xlA[k] = (int)(s & 255u); }
            return;
        }
        const unsigned pg = w & 0xFFFu, rp = w >> 12;
        if (pg == xg) {                                        // root: attach y
            if (atomicCAS(&st[2 * xl], w, yw) == w) {
                st[2 * xl + 1] = yw; st[2 * x0A[k] + 1] = yw;
                act &= ~(1u << k);
            }
        } else if (rp < ry) {                                  // climb
            if (s == xg) st[2 * xl + 1] = w;
            xlA[k] = (int)(pg & 255u);
        } else if (rp > ry) {                                  // splice
            if (atomicCAS(&st[2 * xl], w, yw) == w) {
                st[2 * xl + 1] = yw; st[2 * x0A[k] + 1] = yw;
                xlA[k] = (int)(yw & 255u); x0A[k] = xlA[k]; ywA[k] = w;
            }
        } else { st[2 * x0A[k] + 1] = yw; act &= ~(1u << k); } // p==y
    };

    while (act) {
        unsigned long long ld[2];
#pragma unroll
        for (int k = 0; k < 2; ++k)
            if (act & (1u << k))
                ld[k] = *((volatile unsigned long long*)&st[2 * xlA[k]]);
#pragma unroll
        for (int k = 0; k < 2; ++k)
            if (act & (1u << k)) stepL(k, ld[k]);
    }
    __syncthreads();

    word_g[2 * ((c << 12) + p)]     = st[2 * tid];
    word_g[2 * ((c << 12) + p) + 1] = st[2 * tid + 1];
}

// ---------------------------------------------------------------------------
// K2: two-phase cross-edge assembly + canon + output. 3 blocks x 1024.
// ---------------------------------------------------------------------------
__global__ __launch_bounds__(1024) void ct_assemble(const float* __restrict__ vw,
                                                    const int* __restrict__ rank_g,
                                                    const unsigned* __restrict__ word_g,
                                                    float* __restrict__ out) {
    __shared__ __align__(16) unsigned state[2 * N_PIX];  // 32 KB
    __shared__ float vals[N_PIX];                        // 16 KB
    __shared__ unsigned bmin[15];                        // per-boundary argmin
    const int c   = blockIdx.x;
    const int tid = threadIdx.x;

    if (tid < 15) bmin[tid] = 0xFFFFFFFFu;
    for (int p = tid; p < N_PIX; p += 1024) {
        state[2 * p]     = word_g[2 * ((c << 12) + p)];
        state[2 * p + 1] = word_g[2 * ((c << 12) + p) + 1];
        vals[p]          = vw[p * CH + c];
    }

    // ---- my cross edge (b = tid%15 scatters boundaries across lanes) ----
    int myx = 0; unsigned myyw = 0; int myb = -1, mycol = 0;
    if (tid < 960) {
        myb   = tid % 15;
        mycol = tid / 15;
        int xg = (((myb << 2) + 3) << 6) + mycol;   // row 4b+3
        int yg = xg + 64;                           // row 4b+4
        unsigned rx = (unsigned)rank_g[(c << 12) + xg];
        unsigned ry = (unsigned)rank_g[(c << 12) + yg];
        if (rx > ry) { int t = xg; xg = yg; yg = t; unsigned tr = rx; rx = ry; ry = tr; }
        myx  = xg;
        myyw = (ry << 12) | (unsigned)yg;
    }
    __syncthreads();
    if (tid < 960) atomicMin(&bmin[myb], ((myyw >> 12) << 6) | (unsigned)mycol);
    __syncthreads();

    // ---- shared walk: insert y (packed in yw) into x's root path ----
    auto insert_edge = [&](int x, unsigned yw) {
        int px = -1, x0 = x;
        for (;;) {
            const unsigned long long lv = *((volatile unsigned long long*)&state[2 * x]);
            const unsigned w  = (unsigned)lv;
            const unsigned sk = (unsigned)(lv >> 32);
            const unsigned ry = yw >> 12;
            if (px >= 0) { state[2 * px + 1] = sk; px = -1; }
            const unsigned s = sk & 0xFFFu;
            if (s != (unsigned)x && (sk >> 12) <= ry) {            // hint jump
                if (s == (yw & 0xFFFu)) { state[2 * x0 + 1] = yw; return; }
                px = x; x = (int)s;
                continue;
            }
            const unsigned p = w & 0xFFFu, rp = w >> 12;
            if (p == (unsigned)x) {                                // root: attach y
                if (atomicCAS(&state[2 * x], w, yw) == w) {
                    state[2 * x + 1] = yw; state[2 * x0 + 1] = yw;
                    return;
                }
            } else if (rp < ry) {                                  // climb
                if (s == (unsigned)x) state[2 * x + 1] = w;
                x = (int)p;
            } else if (rp > ry) {                                  // splice
                if (atomicCAS(&state[2 * x], w, yw) == w) {
                    state[2 * x + 1] = yw; state[2 * x0 + 1] = yw;
                    x = (int)(yw & 0xFFFu); x0 = x; yw = w;
                }
            } else { state[2 * x0 + 1] = yw; return; }             // p==y
        }
    };

    // ---- phase A: per-boundary min-ry representative (15 walks, wave 0) ----
    if (tid < 15) {
        const int col = (int)(bmin[tid] & 63u);
        int xg = (((tid << 2) + 3) << 6) + col;
        int yg = xg + 64;
        unsigned rx = (unsigned)rank_g[(c << 12) + xg];
        unsigned ry = (unsigned)rank_g[(c << 12) + yg];
        if (rx > ry) { int t = xg; xg = yg; yg = t; unsigned tr = rx; rx = ry; ry = tr; }
        insert_edge(xg, (ry << 12) | (unsigned)yg);
    }
    __syncthreads();

    // ---- phase B: remaining 945 edges ----
    if (tid < 960 && mycol != (int)(bmin[myb] & 63u))
        insert_edge(myx, myyw);
    __syncthreads();

    // ---- canon (g[p] = climb-from-parent-while-f-equal) + output ----
    for (int p = tid; p < N_PIX; p += 1024) {
        int q = state[2 * p] & 0xFFF;
        const float fq = vals[q];
        for (;;) {
            const int qp = state[2 * q] & 0xFFF;
            if (qp == q) break;
            if (vals[qp] != fq) break;
            q = qp;
        }
        out[(c << 12) + p] = (float)q;
        out[CH * N_PIX + (c << 12) + p] = vals[p];
    }
}

extern "C" void kernel_launch(void* const* d_in, const int* in_sizes, int n_in,
                              void* d_out, int out_size, void* d_ws, size_t ws_size,
                              hipStream_t stream) {
    const float* vw = (const float*)d_in[0];
    float* out = (float*)d_out;

    int*      rank_g = (int*)d_ws;                        // 3*4096 ints
    unsigned* word_g = (unsigned*)(rank_g + CH * N_PIX);  // 2*3*4096 uints

    ct_rank_build<<<48, 256, 0, stream>>>(vw, rank_g, word_g);
    ct_assemble<<<CH, 1024, 0, stream>>>(vw, rank_g, word_g, out);
}

// Round 15
// 229.947 us; speedup vs baseline: 2.1809x; 2.1809x over previous
//
#include <hip/hip_runtime.h>
#include <hip/hip_bf16.h>

// Max-tree (component tree) per channel, 64x64x3. Outputs (float32):
// parents [3,4096] then altitudes [3,4096].
//
// ranks = stable descending sort position (distinct, 0 = highest f) act as
// altitudes; rank-image max-tree's uncompressed pixel-parent == reference's
// (validated r2-r14). Distinct ranks => UNIQUE tree => order-independent
// incremental edge insertion via concurrent CAS splice-walks (r5-r14).
//
// r15 = EXACT r13 structure (free-for-all cross edges — r7/r9/r14 proved
// scheduling constraints lose to concurrency + hints) with the K2 walk
// SOFTWARE-PIPELINED: next-step state load issued as soon as the next node
// is known (hint-jump or climb fast path), hint stores overlapped with the
// in-flight load. Slow path (CAS attach/splice, terminals) reloads.
//
// Safety (r5-r14, schedule/subset/interleaving-agnostic): parw CAS is
// ABA-safe (non-root parent-rank strictly decreases; self word never
// recurs); climb on stale parent safe (splices only INSERT between x and
// parent); skipw hints are ancestors-or-self, jump guarded by rank<=ry
// (ranks strictly ascend along root paths; distinct ranks => rank==ry <=>
// node==y); racy 32-bit hint stores word-atomic; early speculative load
// targets a different address than the step's stores, and any stale value
// read is safe by the same arguments. State stride 8B (16 banks) — never
// 16B (r11 lesson). Canon closed form validated r2-r14.

#define N_PIX 4096
#define CH 3

// ---------------------------------------------------------------------------
// K1: rank + intra-strip concurrent build. 48 blocks x 256 threads.
// ---------------------------------------------------------------------------
__global__ __launch_bounds__(256) void ct_rank_build(const float* __restrict__ vw,
                                                     int* __restrict__ rank_g,
                                                     unsigned* __restrict__ word_g) {
    __shared__ __align__(16) float vals[N_PIX];          // 16 KB
    __shared__ unsigned short rankS[256];
    __shared__ __align__(8) unsigned st[2 * 256];        // 2 KB (parw,skipw)
    const int c    = blockIdx.x >> 4;
    const int seg  = blockIdx.x & 15;
    const int tid  = threadIdx.x;
    const int base = seg << 8;

    for (int i = tid; i < N_PIX; i += 256) vals[i] = vw[i * CH + c];
    __syncthreads();

    // ---- global stable descending rank of this thread's pixel ----
    const int   p  = base + tid;
    const float vp = vals[p];
    int cnt = 0;
    const float4* v4 = reinterpret_cast<const float4*>(vals);
#pragma unroll 4
    for (int j4 = 0; j4 < N_PIX / 4; ++j4) {
        float4 q = v4[j4];
        int j = j4 << 2;
        cnt += (q.x > vp) || ((q.x == vp) && (j     < p));
        cnt += (q.y > vp) || ((q.y == vp) && (j + 1 < p));
        cnt += (q.z > vp) || ((q.z == vp) && (j + 2 < p));
        cnt += (q.w > vp) || ((q.w == vp) && (j + 3 < p));
    }
    rank_g[(c << 12) + p] = cnt;
    rankS[tid] = (unsigned short)cnt;
    const unsigned selfw = ((unsigned)cnt << 12) | (unsigned)p;  // global id
    st[2 * tid]     = selfw;                                     // parw (root)
    st[2 * tid + 1] = selfw;                                     // skipw (self)
    __syncthreads();

    // ---- insert 444 intra-strip edges (2 slots/thread), local indexing ----
    int xlA[2], pxA[2], x0A[2];
    unsigned ywA[2];
    unsigned act = 0;
#pragma unroll
    for (int k = 0; k < 2; ++k) {
        xlA[k] = 0; pxA[k] = -1; x0A[k] = 0; ywA[k] = 0;
        const int e = (k << 8) + tid;
        if (e < 444) {
            int xl, yl;
            if (e < 252) { const int lr = e / 63; xl = (lr << 6) + (e - lr * 63); yl = xl + 1; }
            else         { const int e2 = e - 252; xl = ((e2 >> 6) << 6) + (e2 & 63); yl = xl + 64; }
            unsigned rx = rankS[xl], ry = rankS[yl];
            if (rx > ry) { int t = xl; xl = yl; yl = t; unsigned tr = rx; rx = ry; ry = tr; }
            xlA[k]  = xl;
            x0A[k]  = xl;
            ywA[k]  = (ry << 12) | (unsigned)(base + yl);
            act    |= 1u << k;
        }
    }

    auto stepL = [&](int k, unsigned long long lv) {
        const int      xl = xlA[k];
        const unsigned xg = (unsigned)(base + xl);
        const unsigned yw = ywA[k];
        const unsigned ry = yw >> 12;
        const unsigned w  = (unsigned)lv;
        const unsigned sk = (unsigned)(lv >> 32);
        if (pxA[k] >= 0) { st[2 * pxA[k] + 1] = sk; pxA[k] = -1; }
        const unsigned s = sk & 0xFFFu;
        if (s != xg && (sk >> 12) <= ry) {                     // hint jump
            if (s == (yw & 0xFFFu)) { st[2 * x0A[k] + 1] = yw; act &= ~(1u << k); }
            else { pxA[k] = xl; xlA[k] = (int)(s & 255u); }
            return;
        }
        const unsigned pg = w & 0xFFFu, rp = w >> 12;
        if (pg == xg) {                                        // root: attach y
            if (atomicCAS(&st[2 * xl], w, yw) == w) {
                st[2 * xl + 1] = yw; st[2 * x0A[k] + 1] = yw;
                act &= ~(1u << k);
            }
        } else if (rp < ry) {                                  // climb
            if (s == xg) st[2 * xl + 1] = w;
            xlA[k] = (int)(pg & 255u);
        } else if (rp > ry) {                                  // splice
            if (atomicCAS(&st[2 * xl], w, yw) == w) {
                st[2 * xl + 1] = yw; st[2 * x0A[k] + 1] = yw;
                xlA[k] = (int)(yw & 255u); x0A[k] = xlA[k]; ywA[k] = w;
            }
        } else { st[2 * x0A[k] + 1] = yw; act &= ~(1u << k); } // p==y
    };

    while (act) {
        unsigned long long ld[2];
#pragma unroll
        for (int k = 0; k < 2; ++k)
            if (act & (1u << k))
                ld[k] = *((volatile unsigned long long*)&st[2 * xlA[k]]);
#pragma unroll
        for (int k = 0; k < 2; ++k)
            if (act & (1u << k)) stepL(k, ld[k]);
    }
    __syncthreads();

    word_g[2 * ((c << 12) + p)]     = st[2 * tid];
    word_g[2 * ((c << 12) + p) + 1] = st[2 * tid + 1];
}

// ---------------------------------------------------------------------------
// K2: cross-edge assembly (pipelined walks) + canon + output. 3 blocks.
// ---------------------------------------------------------------------------
__global__ __launch_bounds__(1024) void ct_assemble(const float* __restrict__ vw,
                                                    const int* __restrict__ rank_g,
                                                    const unsigned* __restrict__ word_g,
                                                    float* __restrict__ out) {
    __shared__ __align__(16) unsigned state[2 * N_PIX];  // 32 KB
    __shared__ float vals[N_PIX];                        // 16 KB
    const int c   = blockIdx.x;
    const int tid = threadIdx.x;

    for (int p = tid; p < N_PIX; p += 1024) {
        state[2 * p]     = word_g[2 * ((c << 12) + p)];
        state[2 * p + 1] = word_g[2 * ((c << 12) + p) + 1];
        vals[p]          = vw[p * CH + c];
    }
    __syncthreads();

    // ---- one cross edge per thread (tid < 960), boundaries scattered ----
    if (tid < 960) {
        const int b   = tid % 15;
        const int col = tid / 15;
        int xg = (((b << 2) + 3) << 6) + col;   // row 4b+3
        int yg = xg + 64;                       // row 4b+4
        unsigned rx = (unsigned)rank_g[(c << 12) + xg];
        unsigned ry = (unsigned)rank_g[(c << 12) + yg];
        if (rx > ry) { int t = xg; xg = yg; yg = t; unsigned tr = rx; rx = ry; ry = tr; }

        int x = xg, x0 = xg, px = -1;
        unsigned yw = (ry << 12) | (unsigned)yg;
        volatile unsigned long long* vst = (volatile unsigned long long*)state;
        unsigned long long lv = vst[x];
        bool on = true;
        while (on) {
            const unsigned w   = (unsigned)lv;
            const unsigned sk  = (unsigned)(lv >> 32);
            const unsigned ryc = yw >> 12;
            const unsigned ylo = yw & 0xFFFu;
            const unsigned s   = sk & 0xFFFu;
            const unsigned p   = w & 0xFFFu;
            const unsigned rp  = w >> 12;

            const bool hjump = (s != (unsigned)x) && ((sk >> 12) <= ryc);
            const bool climb = !hjump && (p != (unsigned)x) && (rp < ryc);

            if (hjump | climb) {
                const int nx = (int)(hjump ? s : p);
                const bool term = hjump && (s == ylo);
                unsigned long long lvn = 0;
                if (!term) lvn = vst[nx];                    // issue early!
                // overlapped stores while lvn is in flight
                if (px >= 0) { state[2 * px + 1] = sk; px = -1; }
                if (term) { state[2 * x0 + 1] = yw; on = false; }
                else {
                    if (hjump) px = x;
                    else if (s == (unsigned)x) state[2 * x + 1] = w;  // memo
                    x = nx; lv = lvn;
                }
                continue;
            }

            // slow path: root attach / splice / p==y
            if (px >= 0) { state[2 * px + 1] = sk; px = -1; }
            if (p == (unsigned)x) {                          // root: attach y
                if (atomicCAS(&state[2 * x], w, yw) == w) {
                    state[2 * x + 1] = yw; state[2 * x0 + 1] = yw;
                    on = false;
                } else lv = vst[x];
            } else if (rp > ryc) {                           // splice
                if (atomicCAS(&state[2 * x], w, yw) == w) {
                    state[2 * x + 1] = yw; state[2 * x0 + 1] = yw;
                    x = (int)ylo; x0 = x; yw = w;
                }
                lv = vst[x];
            } else {                                         // rp==ryc => p==y
                state[2 * x0 + 1] = yw;
                on = false;
            }
        }
    }
    __syncthreads();

    // ---- canon (g[p] = climb-from-parent-while-f-equal) + output ----
    for (int p = tid; p < N_PIX; p += 1024) {
        int q = state[2 * p] & 0xFFF;
        const float fq = vals[q];
        for (;;) {
            const int qp = state[2 * q] & 0xFFF;
            if (qp == q) break;
            if (vals[qp] != fq) break;
            q = qp;
        }
        out[(c << 12) + p] = (float)q;
        out[CH * N_PIX + (c << 12) + p] = vals[p];
    }
}

extern "C" void kernel_launch(void* const* d_in, const int* in_sizes, int n_in,
                              void* d_out, int out_size, void* d_ws, size_t ws_size,
                              hipStream_t stream) {
    const float* vw = (const float*)d_in[0];
    float* out = (float*)d_out;

    int*      rank_g = (int*)d_ws;                        // 3*4096 ints
    unsigned* word_g = (unsigned*)(rank_g + CH * N_PIX);  // 2*3*4096 uints

    ct_rank_build<<<48, 256, 0, stream>>>(vw, rank_g, word_g);
    ct_assemble<<<CH, 1024, 0, stream>>>(vw, rank_g, word_g, out);
}

// Round 16
// 147.764 us; speedup vs baseline: 3.3938x; 1.5562x over previous
//
#include <hip/hip_runtime.h>
#include <hip/hip_bf16.h>

// Max-tree (component tree) per channel, 64x64x3. Outputs (float32):
// parents [3,4096] then altitudes [3,4096].
//
// ranks = stable descending sort position (distinct, 0 = highest f) act as
// altitudes; rank-image max-tree's uncompressed pixel-parent == reference's
// (validated r2-r15). Distinct ranks => UNIQUE tree => order-independent
// incremental edge insertion via concurrent CAS splice-walks (r5-r15).
//
// r16 pipeline:
//  ct_rank    (768 blocks): blocked O(N^2) stable rank, (c,si,sj) partial
//             counts + atomicAdd — 16x the parallelism of the fused r15 scan.
//  ct_build   (48 blocks): intra-strip concurrent CAS build (r15 verbatim).
//  ct_assemble(3 blocks): 960 cross edges, software-pipelined walks (r15) +
//             canon closed form + output.
//
// Safety (r5-r15, schedule/subset/interleaving-agnostic): parw CAS is
// ABA-safe (non-root parent-rank strictly decreases; self word never
// recurs); climb on stale parent safe (splices only INSERT between x and
// parent); skipw hints are ancestors-or-self, jump guarded by rank<=ry
// (ranks strictly ascend along root paths; distinct ranks => rank==ry <=>
// node==y); racy 32-bit hint stores word-atomic; speculative next-load safe
// (different address than the step's stores; stale values re-validated by
// CAS). State stride 8B (16 banks) — never 16B (r11 lesson).
// Canon closed form g[p] = climb-from-parent-while-f-equal (validated r2-r15).

#define N_PIX 4096
#define CH 3

// ---------------------------------------------------------------------------
// K1a: blocked stable rank. 768 blocks = (c, si, sj), 256 threads.
// rank(p) = #{f[q]>f[p]} + #{f[q]==f[p], q<p}, accumulated by atomicAdd.
// ---------------------------------------------------------------------------
__global__ __launch_bounds__(256) void ct_rank(const float* __restrict__ vw,
                                               int* __restrict__ rank_g) {
    __shared__ __align__(16) float seg[256];
    const int b   = blockIdx.x;
    const int c   = b >> 8;
    const int si  = (b >> 4) & 15;
    const int sj  = b & 15;
    const int tid = threadIdx.x;

    seg[tid] = vw[((sj << 8) + tid) * CH + c];
    __syncthreads();

    const int   p  = (si << 8) + tid;
    const float vp = vw[p * CH + c];
    const int jbase = sj << 8;
    int cnt = 0;
    const float4* v4 = reinterpret_cast<const float4*>(seg);
#pragma unroll 8
    for (int j4 = 0; j4 < 64; ++j4) {
        float4 q = v4[j4];
        int j = jbase + (j4 << 2);
        cnt += (q.x > vp) || ((q.x == vp) && (j     < p));
        cnt += (q.y > vp) || ((q.y == vp) && (j + 1 < p));
        cnt += (q.z > vp) || ((q.z == vp) && (j + 2 < p));
        cnt += (q.w > vp) || ((q.w == vp) && (j + 3 < p));
    }
    atomicAdd(&rank_g[(c << 12) + p], cnt);
}

// ---------------------------------------------------------------------------
// K1b: intra-strip concurrent build. 48 blocks x 256 threads (r15 verbatim).
// ---------------------------------------------------------------------------
__global__ __launch_bounds__(256) void ct_build(const int* __restrict__ rank_g,
                                                unsigned* __restrict__ word_g) {
    __shared__ unsigned short rankS[256];
    __shared__ __align__(8) unsigned st[2 * 256];        // 2 KB (parw,skipw)
    const int c    = blockIdx.x >> 4;
    const int seg  = blockIdx.x & 15;
    const int tid  = threadIdx.x;
    const int base = seg << 8;
    const int p    = base + tid;

    const unsigned r = (unsigned)rank_g[(c << 12) + p];
    rankS[tid] = (unsigned short)r;
    const unsigned selfw = (r << 12) | (unsigned)p;      // global id
    st[2 * tid]     = selfw;                             // parw (root)
    st[2 * tid + 1] = selfw;                             // skipw (self)
    __syncthreads();

    // ---- insert 444 intra-strip edges (2 slots/thread), local indexing ----
    int xlA[2], pxA[2], x0A[2];
    unsigned ywA[2];
    unsigned act = 0;
#pragma unroll
    for (int k = 0; k < 2; ++k) {
        xlA[k] = 0; pxA[k] = -1; x0A[k] = 0; ywA[k] = 0;
        const int e = (k << 8) + tid;
        if (e < 444) {
            int xl, yl;
            if (e < 252) { const int lr = e / 63; xl = (lr << 6) + (e - lr * 63); yl = xl + 1; }
            else         { const int e2 = e - 252; xl = ((e2 >> 6) << 6) + (e2 & 63); yl = xl + 64; }
            unsigned rx = rankS[xl], ry = rankS[yl];
            if (rx > ry) { int t = xl; xl = yl; yl = t; unsigned tr = rx; rx = ry; ry = tr; }
            xlA[k]  = xl;
            x0A[k]  = xl;
            ywA[k]  = (ry << 12) | (unsigned)(base + yl);
            act    |= 1u << k;
        }
    }

    auto stepL = [&](int k, unsigned long long lv) {
        const int      xl = xlA[k];
        const unsigned xg = (unsigned)(base + xl);
        const unsigned yw = ywA[k];
        const unsigned ry = yw >> 12;
        const unsigned w  = (unsigned)lv;
        const unsigned sk = (unsigned)(lv >> 32);
        if (pxA[k] >= 0) { st[2 * pxA[k] + 1] = sk; pxA[k] = -1; }
        const unsigned s = sk & 0xFFFu;
        if (s != xg && (sk >> 12) <= ry) {                     // hint jump
            if (s == (yw & 0xFFFu)) { st[2 * x0A[k] + 1] = yw; act &= ~(1u << k); }
            else { pxA[k] = xl; xlA[k] = (int)(s & 255u); }
            return;
        }
        const unsigned pg = w & 0xFFFu, rp = w >> 12;
        if (pg == xg) {                                        // root: attach y
            if (atomicCAS(&st[2 * xl], w, yw) == w) {
                st[2 * xl + 1] = yw; st[2 * x0A[k] + 1] = yw;
                act &= ~(1u << k);
            }
        } else if (rp < ry) {                                  // climb
            if (s == xg) st[2 * xl + 1] = w;
            xlA[k] = (int)(pg & 255u);
        } else if (rp > ry) {                                  // splice
            if (atomicCAS(&st[2 * xl], w, yw) == w) {
                st[2 * xl + 1] = yw; st[2 * x0A[k] + 1] = yw;
                xlA[k] = (int)(yw & 255u); x0A[k] = xlA[k]; ywA[k] = w;
            }
        } else { st[2 * x0A[k] + 1] = yw; act &= ~(1u << k); } // p==y
    };

    while (act) {
        unsigned long long ld[2];
#pragma unroll
        for (int k = 0; k < 2; ++k)
            if (act & (1u << k))
                ld[k] = *((volatile unsigned long long*)&st[2 * xlA[k]]);
#pragma unroll
        for (int k = 0; k < 2; ++k)
            if (act & (1u << k)) stepL(k, ld[k]);
    }
    __syncthreads();

    word_g[2 * ((c << 12) + p)]     = st[2 * tid];
    word_g[2 * ((c << 12) + p) + 1] = st[2 * tid + 1];
}

// ---------------------------------------------------------------------------
// K2: cross-edge assembly (pipelined walks) + canon + output. 3 blocks.
// ---------------------------------------------------------------------------
__global__ __launch_bounds__(1024) void ct_assemble(const float* __restrict__ vw,
                                                    const int* __restrict__ rank_g,
                                                    const unsigned* __restrict__ word_g,
                                                    float* __restrict__ out) {
    __shared__ __align__(16) unsigned state[2 * N_PIX];  // 32 KB
    __shared__ float vals[N_PIX];                        // 16 KB
    const int c   = blockIdx.x;
    const int tid = threadIdx.x;

    for (int p = tid; p < N_PIX; p += 1024) {
        state[2 * p]     = word_g[2 * ((c << 12) + p)];
        state[2 * p + 1] = word_g[2 * ((c << 12) + p) + 1];
        vals[p]          = vw[p * CH + c];
    }
    __syncthreads();

    // ---- one cross edge per thread (tid < 960), boundaries scattered ----
    if (tid < 960) {
        const int b   = tid % 15;
        const int col = tid / 15;
        int xg = (((b << 2) + 3) << 6) + col;   // row 4b+3
        int yg = xg + 64;                       // row 4b+4
        unsigned rx = (unsigned)rank_g[(c << 12) + xg];
        unsigned ry = (unsigned)rank_g[(c << 12) + yg];
        if (rx > ry) { int t = xg; xg = yg; yg = t; unsigned tr = rx; rx = ry; ry = tr; }

        int x = xg, x0 = xg, px = -1;
        unsigned yw = (ry << 12) | (unsigned)yg;
        volatile unsigned long long* vst = (volatile unsigned long long*)state;
        unsigned long long lv = vst[x];
        bool on = true;
        while (on) {
            const unsigned w   = (unsigned)lv;
            const unsigned sk  = (unsigned)(lv >> 32);
            const unsigned ryc = yw >> 12;
            const unsigned ylo = yw & 0xFFFu;
            const unsigned s   = sk & 0xFFFu;
            const unsigned p   = w & 0xFFFu;
            const unsigned rp  = w >> 12;

            const bool hjump = (s != (unsigned)x) && ((sk >> 12) <= ryc);
            const bool climb = !hjump && (p != (unsigned)x) && (rp < ryc);

            if (hjump | climb) {
                const int nx = (int)(hjump ? s : p);
                const bool term = hjump && (s == ylo);
                unsigned long long lvn = 0;
                if (!term) lvn = vst[nx];                    // issue early!
                // overlapped stores while lvn is in flight
                if (px >= 0) { state[2 * px + 1] = sk; px = -1; }
                if (term) { state[2 * x0 + 1] = yw; on = false; }
                else {
                    if (hjump) px = x;
                    else if (s == (unsigned)x) state[2 * x + 1] = w;  // memo
                    x = nx; lv = lvn;
                }
                continue;
            }

            // slow path: root attach / splice / p==y
            if (px >= 0) { state[2 * px + 1] = sk; px = -1; }
            if (p == (unsigned)x) {                          // root: attach y
                if (atomicCAS(&state[2 * x], w, yw) == w) {
                    state[2 * x + 1] = yw; state[2 * x0 + 1] = yw;
                    on = false;
                } else lv = vst[x];
            } else if (rp > ryc) {                           // splice
                if (atomicCAS(&state[2 * x], w, yw) == w) {
                    state[2 * x + 1] = yw; state[2 * x0 + 1] = yw;
                    x = (int)ylo; x0 = x; yw = w;
                }
                lv = vst[x];
            } else {                                         // rp==ryc => p==y
                state[2 * x0 + 1] = yw;
                on = false;
            }
        }
    }
    __syncthreads();

    // ---- canon (g[p] = climb-from-parent-while-f-equal) + output ----
    for (int p = tid; p < N_PIX; p += 1024) {
        int q = state[2 * p] & 0xFFF;
        const float fq = vals[q];
        for (;;) {
            const int qp = state[2 * q] & 0xFFF;
            if (qp == q) break;
            if (vals[qp] != fq) break;
            q = qp;
        }
        out[(c << 12) + p] = (float)q;
        out[CH * N_PIX + (c << 12) + p] = vals[p];
    }
}

extern "C" void kernel_launch(void* const* d_in, const int* in_sizes, int n_in,
                              void* d_out, int out_size, void* d_ws, size_t ws_size,
                              hipStream_t stream) {
    const float* vw = (const float*)d_in[0];
    float* out = (float*)d_out;

    int*      rank_g = (int*)d_ws;                        // 3*4096 ints
    unsigned* word_g = (unsigned*)(rank_g + CH * N_PIX);  // 2*3*4096 uints

    hipMemsetAsync(rank_g, 0, CH * N_PIX * sizeof(int), stream);
    ct_rank    <<<768, 256, 0, stream>>>(vw, rank_g);
    ct_build   <<<48, 256, 0, stream>>>(rank_g, word_g);
    ct_assemble<<<CH, 1024, 0, stream>>>(vw, rank_g, word_g, out);
}

// Round 17
// 147.601 us; speedup vs baseline: 3.3976x; 1.0011x over previous
//
#include <hip/hip_runtime.h>
#include <hip/hip_bf16.h>

// Max-tree (component tree) per channel, 64x64x3. Outputs (float32):
// parents [3,4096] then altitudes [3,4096].
//
// ranks = stable descending sort position (distinct, 0 = highest f) act as
// altitudes; rank-image max-tree's uncompressed pixel-parent == reference's
// (validated r2-r16). Distinct ranks => UNIQUE tree => order-independent
// incremental edge insertion via concurrent CAS splice-walks (r5-r16).
//
// r17 = r16 with ct_assemble's edge->thread map changed to WAVE = BOUNDARY
// (b = tid>>6, col = tid&63): the 15 deep interleaves run in 15 separate
// waves; lanes of a wave share one trunk (lockstep hint cooperation, less
// divergence). Free-for-all preserved — no barriers, no serialization.
//
// Safety (r5-r16, schedule/subset/interleaving-agnostic): parw CAS is
// ABA-safe (non-root parent-rank strictly decreases; self word never
// recurs); climb on stale parent safe (splices only INSERT between x and
// parent); skipw hints are ancestors-or-self, jump guarded by rank<=ry
// (ranks strictly ascend along root paths; distinct ranks => rank==ry <=>
// node==y); racy 32-bit hint stores word-atomic; speculative next-load safe
// (different address than the step's stores; stale values re-validated by
// CAS). State stride 8B (16 banks) — never 16B (r11 lesson).
// Canon closed form g[p] = climb-from-parent-while-f-equal (validated r2-r16).

#define N_PIX 4096
#define CH 3

// ---------------------------------------------------------------------------
// K1a: blocked stable rank. 768 blocks = (c, si, sj), 256 threads.
// rank(p) = #{f[q]>f[p]} + #{f[q]==f[p], q<p}, accumulated by atomicAdd.
// ---------------------------------------------------------------------------
__global__ __launch_bounds__(256) void ct_rank(const float* __restrict__ vw,
                                               int* __restrict__ rank_g) {
    __shared__ __align__(16) float seg[256];
    const int b   = blockIdx.x;
    const int c   = b >> 8;
    const int si  = (b >> 4) & 15;
    const int sj  = b & 15;
    const int tid = threadIdx.x;

    seg[tid] = vw[((sj << 8) + tid) * CH + c];
    __syncthreads();

    const int   p  = (si << 8) + tid;
    const float vp = vw[p * CH + c];
    const int jbase = sj << 8;
    int cnt = 0;
    const float4* v4 = reinterpret_cast<const float4*>(seg);
#pragma unroll 8
    for (int j4 = 0; j4 < 64; ++j4) {
        float4 q = v4[j4];
        int j = jbase + (j4 << 2);
        cnt += (q.x > vp) || ((q.x == vp) && (j     < p));
        cnt += (q.y > vp) || ((q.y == vp) && (j + 1 < p));
        cnt += (q.z > vp) || ((q.z == vp) && (j + 2 < p));
        cnt += (q.w > vp) || ((q.w == vp) && (j + 3 < p));
    }
    atomicAdd(&rank_g[(c << 12) + p], cnt);
}

// ---------------------------------------------------------------------------
// K1b: intra-strip concurrent build. 48 blocks x 256 threads (r16 verbatim).
// ---------------------------------------------------------------------------
__global__ __launch_bounds__(256) void ct_build(const int* __restrict__ rank_g,
                                                unsigned* __restrict__ word_g) {
    __shared__ unsigned short rankS[256];
    __shared__ __align__(8) unsigned st[2 * 256];        // 2 KB (parw,skipw)
    const int c    = blockIdx.x >> 4;
    const int seg  = blockIdx.x & 15;
    const int tid  = threadIdx.x;
    const int base = seg << 8;
    const int p    = base + tid;

    const unsigned r = (unsigned)rank_g[(c << 12) + p];
    rankS[tid] = (unsigned short)r;
    const unsigned selfw = (r << 12) | (unsigned)p;      // global id
    st[2 * tid]     = selfw;                             // parw (root)
    st[2 * tid + 1] = selfw;                             // skipw (self)
    __syncthreads();

    // ---- insert 444 intra-strip edges (2 slots/thread), local indexing ----
    int xlA[2], pxA[2], x0A[2];
    unsigned ywA[2];
    unsigned act = 0;
#pragma unroll
    for (int k = 0; k < 2; ++k) {
        xlA[k] = 0; pxA[k] = -1; x0A[k] = 0; ywA[k] = 0;
        const int e = (k << 8) + tid;
        if (e < 444) {
            int xl, yl;
            if (e < 252) { const int lr = e / 63; xl = (lr << 6) + (e - lr * 63); yl = xl + 1; }
            else         { const int e2 = e - 252; xl = ((e2 >> 6) << 6) + (e2 & 63); yl = xl + 64; }
            unsigned rx = rankS[xl], ry = rankS[yl];
            if (rx > ry) { int t = xl; xl = yl; yl = t; unsigned tr = rx; rx = ry; ry = tr; }
            xlA[k]  = xl;
            x0A[k]  = xl;
            ywA[k]  = (ry << 12) | (unsigned)(base + yl);
            act    |= 1u << k;
        }
    }

    auto stepL = [&](int k, unsigned long long lv) {
        const int      xl = xlA[k];
        const unsigned xg = (unsigned)(base + xl);
        const unsigned yw = ywA[k];
        const unsigned ry = yw >> 12;
        const unsigned w  = (unsigned)lv;
        const unsigned sk = (unsigned)(lv >> 32);
        if (pxA[k] >= 0) { st[2 * pxA[k] + 1] = sk; pxA[k] = -1; }
        const unsigned s = sk & 0xFFFu;
        if (s != xg && (sk >> 12) <= ry) {                     // hint jump
            if (s == (yw & 0xFFFu)) { st[2 * x0A[k] + 1] = yw; act &= ~(1u << k); }
            else { pxA[k] = xl; xlA[k] = (int)(s & 255u); }
            return;
        }
        const unsigned pg = w & 0xFFFu, rp = w >> 12;
        if (pg == xg) {                                        // root: attach y
            if (atomicCAS(&st[2 * xl], w, yw) == w) {
                st[2 * xl + 1] = yw; st[2 * x0A[k] + 1] = yw;
                act &= ~(1u << k);
            }
        } else if (rp < ry) {                                  // climb
            if (s == xg) st[2 * xl + 1] = w;
            xlA[k] = (int)(pg & 255u);
        } else if (rp > ry) {                                  // splice
            if (atomicCAS(&st[2 * xl], w, yw) == w) {
                st[2 * xl + 1] = yw; st[2 * x0A[k] + 1] = yw;
                xlA[k] = (int)(yw & 255u); x0A[k] = xlA[k]; ywA[k] = w;
            }
        } else { st[2 * x0A[k] + 1] = yw; act &= ~(1u << k); } // p==y
    };

    while (act) {
        unsigned long long ld[2];
#pragma unroll
        for (int k = 0; k < 2; ++k)
            if (act & (1u << k))
                ld[k] = *((volatile unsigned long long*)&st[2 * xlA[k]]);
#pragma unroll
        for (int k = 0; k < 2; ++k)
            if (act & (1u << k)) stepL(k, ld[k]);
    }
    __syncthreads();

    word_g[2 * ((c << 12) + p)]     = st[2 * tid];
    word_g[2 * ((c << 12) + p) + 1] = st[2 * tid + 1];
}

// ---------------------------------------------------------------------------
// K2: cross-edge assembly (pipelined walks, wave=boundary) + canon + output.
// 3 blocks x 1024 threads.
// ---------------------------------------------------------------------------
__global__ __launch_bounds__(1024) void ct_assemble(const float* __restrict__ vw,
                                                    const int* __restrict__ rank_g,
                                                    const unsigned* __restrict__ word_g,
                                                    float* __restrict__ out) {
    __shared__ __align__(16) unsigned state[2 * N_PIX];  // 32 KB
    __shared__ float vals[N_PIX];                        // 16 KB
    const int c   = blockIdx.x;
    const int tid = threadIdx.x;

    for (int p = tid; p < N_PIX; p += 1024) {
        state[2 * p]     = word_g[2 * ((c << 12) + p)];
        state[2 * p + 1] = word_g[2 * ((c << 12) + p) + 1];
        vals[p]          = vw[p * CH + c];
    }
    __syncthreads();

    // ---- one cross edge per thread; WAVE = BOUNDARY (b = tid>>6) ----
    if (tid < 960) {
        const int b   = tid >> 6;               // boundary 0..14 (one wave each)
        const int col = tid & 63;
        int xg = (((b << 2) + 3) << 6) + col;   // row 4b+3
        int yg = xg + 64;                       // row 4b+4
        unsigned rx = (unsigned)rank_g[(c << 12) + xg];
        unsigned ry = (unsigned)rank_g[(c << 12) + yg];
        if (rx > ry) { int t = xg; xg = yg; yg = t; unsigned tr = rx; rx = ry; ry = tr; }

        int x = xg, x0 = xg, px = -1;
        unsigned yw = (ry << 12) | (unsigned)yg;
        volatile unsigned long long* vst = (volatile unsigned long long*)state;
        unsigned long long lv = vst[x];
        bool on = true;
        while (on) {
            const unsigned w   = (unsigned)lv;
            const unsigned sk  = (unsigned)(lv >> 32);
            const unsigned ryc = yw >> 12;
            const unsigned ylo = yw & 0xFFFu;
            const unsigned s   = sk & 0xFFFu;
            const unsigned p   = w & 0xFFFu;
            const unsigned rp  = w >> 12;

            const bool hjump = (s != (unsigned)x) && ((sk >> 12) <= ryc);
            const bool climb = !hjump && (p != (unsigned)x) && (rp < ryc);

            if (hjump | climb) {
                const int nx = (int)(hjump ? s : p);
                const bool term = hjump && (s == ylo);
                unsigned long long lvn = 0;
                if (!term) lvn = vst[nx];                    // issue early!
                // overlapped stores while lvn is in flight
                if (px >= 0) { state[2 * px + 1] = sk; px = -1; }
                if (term) { state[2 * x0 + 1] = yw; on = false; }
                else {
                    if (hjump) px = x;
                    else if (s == (unsigned)x) state[2 * x + 1] = w;  // memo
                    x = nx; lv = lvn;
                }
                continue;
            }

            // slow path: root attach / splice / p==y
            if (px >= 0) { state[2 * px + 1] = sk; px = -1; }
            if (p == (unsigned)x) {                          // root: attach y
                if (atomicCAS(&state[2 * x], w, yw) == w) {
                    state[2 * x + 1] = yw; state[2 * x0 + 1] = yw;
                    on = false;
                } else lv = vst[x];
            } else if (rp > ryc) {                           // splice
                if (atomicCAS(&state[2 * x], w, yw) == w) {
                    state[2 * x + 1] = yw; state[2 * x0 + 1] = yw;
                    x = (int)ylo; x0 = x; yw = w;
                }
                lv = vst[x];
            } else {                                         // rp==ryc => p==y
                state[2 * x0 + 1] = yw;
                on = false;
            }
        }
    }
    __syncthreads();

    // ---- canon (g[p] = climb-from-parent-while-f-equal) + output ----
    for (int p = tid; p < N_PIX; p += 1024) {
        int q = state[2 * p] & 0xFFF;
        const float fq = vals[q];
        for (;;) {
            const int qp = state[2 * q] & 0xFFF;
            if (qp == q) break;
            if (vals[qp] != fq) break;
            q = qp;
        }
        out[(c << 12) + p] = (float)q;
        out[CH * N_PIX + (c << 12) + p] = vals[p];
    }
}

extern "C" void kernel_launch(void* const* d_in, const int* in_sizes, int n_in,
                              void* d_out, int out_size, void* d_ws, size_t ws_size,
                              hipStream_t stream) {
    const float* vw = (const float*)d_in[0];
    float* out = (float*)d_out;

    int*      rank_g = (int*)d_ws;                        // 3*4096 ints
    unsigned* word_g = (unsigned*)(rank_g + CH * N_PIX);  // 2*3*4096 uints

    hipMemsetAsync(rank_g, 0, CH * N_PIX * sizeof(int), stream);
    ct_rank    <<<768, 256, 0, stream>>>(vw, rank_g);
    ct_build   <<<48, 256, 0, stream>>>(rank_g, word_g);
    ct_assemble<<<CH, 1024, 0, stream>>>(vw, rank_g, word_g, out);
}